// Round 21
// baseline (94.863 us; speedup 1.0000x reference)
//
#include <hip/hip_runtime.h>

#define N_NODES 50000
#define N_EDGES 800000
#define D_IN 256
#define D_OUT 64
#define NEG_SLOPE 0.01f

#define NB 196      // coarse buckets: bucket = row >> 8
#define CHUNKS 250  // scatter blocks (~1 per CU)
#define CE 3200     // edges per scatter block (250*3200 = 800000 exactly)

typedef unsigned short ushort;
typedef short short8 __attribute__((ext_vector_type(8)));
typedef float f32x4 __attribute__((ext_vector_type(4)));

// Split f32 into hi/lo bf16 (truncation): a ≈ hi + lo, |err| ~ 2^-16 rel.
__device__ __forceinline__ void split2(float a, ushort& hi, ushort& lo) {
  unsigned ub = __float_as_uint(a);
  hi = (ushort)(ub >> 16);
  float hf = __uint_as_float(ub & 0xFFFF0000u);
  lo = (ushort)(__float_as_uint(a - hf) >> 16);
}

// f32 -> bf16 round-to-nearest-even
__device__ __forceinline__ ushort rne_bf16(float a) {
  unsigned u = __float_as_uint(a);
  return (ushort)((u + 0x7FFFu + ((u >> 16) & 1u)) >> 16);
}

// Monotone float<->uint encoding (atomicMax-able)
__device__ __forceinline__ unsigned enc_f32(float f) {
  unsigned u = __float_as_uint(f);
  return (u & 0x80000000u) ? ~u : (u | 0x80000000u);
}
__device__ __forceinline__ float dec_f32(unsigned u) {
  return (u & 0x80000000u) ? __uint_as_float(u ^ 0x80000000u)
                           : __uint_as_float(~u);
}

__device__ __forceinline__ float hload(const ushort* hb, unsigned col,
                                       int lane) {
  return __uint_as_float((unsigned)hb[(size_t)col * D_OUT + lane] << 16);
}

// ---------------- Kernel P: fused W-split (blocks 0..7) + histogram --------
__global__ __launch_bounds__(256) void k_prep(
    const float* __restrict__ W, short8* __restrict__ Bh,
    short8* __restrict__ Bl, const int* __restrict__ rows,
    unsigned* __restrict__ hist) {
  __shared__ unsigned lhist[NB];
  if (blockIdx.x < 8) {
    int t = blockIdx.x * 256 + threadIdx.x;  // 0..2047
    int lane = t & 63;
    int ct = (t >> 6) & 3;
    int ks = t >> 8;
    int k0 = ks * 32 + (lane >> 4) * 8;
    int col = ct * 16 + (lane & 15);
    short8 h8, l8;
#pragma unroll
    for (int j = 0; j < 8; ++j) {
      ushort hi, lo;
      split2(W[(size_t)(k0 + j) * D_OUT + col], hi, lo);
      h8[j] = (short)hi;
      l8[j] = (short)lo;
    }
    Bh[t] = h8;
    Bl[t] = l8;
  } else {
    int chunk = blockIdx.x - 8;
    for (int b = threadIdx.x; b < NB; b += 256) lhist[b] = 0u;
    __syncthreads();
    int base = chunk * CE;
    for (int i = threadIdx.x * 4; i < CE; i += 1024) {
      int4 r4 = *reinterpret_cast<const int4*>(&rows[base + i]);
      atomicAdd(&lhist[r4.x >> 8], 1u);
      atomicAdd(&lhist[r4.y >> 8], 1u);
      atomicAdd(&lhist[r4.z >> 8], 1u);
      atomicAdd(&lhist[r4.w >> 8], 1u);
    }
    __syncthreads();
    for (int b = threadIdx.x; b < NB; b += 256)
      hist[b * CHUNKS + chunk] = lhist[b];
  }
}

// ---------------- Kernel 1: h = X*W + b via bf16 MFMA (hi/lo split) --------
__global__ __launch_bounds__(256) void k_gemm_mfma(
    const float* __restrict__ feat, const short8* __restrict__ Bh,
    const short8* __restrict__ Bl, const float* __restrict__ bias,
    const float* __restrict__ a1w, const float* __restrict__ a1b,
    const float* __restrict__ a2w, const float* __restrict__ a2b,
    ushort* __restrict__ hb, float* __restrict__ a1, float* __restrict__ a2) {
  int wid = (blockIdx.x * 256 + threadIdx.x) >> 6;
  int lane = threadIdx.x & 63;
  if (wid >= N_NODES / 16) return;  // 3125 waves exactly
  int row0 = wid * 16;

  int arow = row0 + (lane & 15);
  const float* fp = feat + (size_t)arow * D_IN + ((lane >> 4) * 8);

  f32x4 acc[4];
#pragma unroll
  for (int ct = 0; ct < 4; ++ct) acc[ct] = (f32x4){0.f, 0.f, 0.f, 0.f};

#pragma unroll
  for (int ks = 0; ks < 8; ++ks) {
    float4 v0 = *reinterpret_cast<const float4*>(fp + ks * 32);
    float4 v1 = *reinterpret_cast<const float4*>(fp + ks * 32 + 4);
    float av[8] = {v0.x, v0.y, v0.z, v0.w, v1.x, v1.y, v1.z, v1.w};
    short8 ah, al;
#pragma unroll
    for (int j = 0; j < 8; ++j) {
      ushort hi, lo;
      split2(av[j], hi, lo);
      ah[j] = (short)hi;
      al[j] = (short)lo;
    }
#pragma unroll
    for (int ct = 0; ct < 4; ++ct) {
      short8 bh = Bh[(ks * 4 + ct) * 64 + lane];
      short8 bl = Bl[(ks * 4 + ct) * 64 + lane];
      acc[ct] = __builtin_amdgcn_mfma_f32_16x16x32_bf16(ah, bh, acc[ct], 0, 0, 0);
      acc[ct] = __builtin_amdgcn_mfma_f32_16x16x32_bf16(ah, bl, acc[ct], 0, 0, 0);
      acc[ct] = __builtin_amdgcn_mfma_f32_16x16x32_bf16(al, bh, acc[ct], 0, 0, 0);
    }
  }

  int lo16 = lane & 15;
  int hi4 = (lane >> 4) * 4;
  float bv[4], w1[4], w2[4];
#pragma unroll
  for (int ct = 0; ct < 4; ++ct) {
    bv[ct] = bias[ct * 16 + lo16];
    w1[ct] = a1w[ct * 16 + lo16];
    w2[ct] = a2w[ct * 16 + lo16];
  }
  float b1 = a1b[0], b2 = a2b[0];

#pragma unroll
  for (int r = 0; r < 4; ++r) {
    int row = row0 + hi4 + r;
    float s1 = 0.f, s2 = 0.f;
#pragma unroll
    for (int ct = 0; ct < 4; ++ct) {
      float hv = acc[ct][r] + bv[ct];
      hb[(size_t)row * D_OUT + ct * 16 + lo16] = rne_bf16(hv);
      s1 = fmaf(hv, w1[ct], s1);
      s2 = fmaf(hv, w2[ct], s2);
    }
#pragma unroll
    for (int off = 1; off < 16; off <<= 1) {
      s1 += __shfl_xor(s1, off);
      s2 += __shfl_xor(s2, off);
    }
    if (lo16 == 0) {
      a1[row] = s1 + b1;
      a2[row] = s2 + b2;
    }
  }
}

// ---------------- Kernel H1.5: bucket totals -> exclusive bases bb[] -------
__global__ __launch_bounds__(256) void k_bucket_base(
    const unsigned* __restrict__ hist, unsigned* __restrict__ bb,
    unsigned* __restrict__ start) {
  int b = threadIdx.x;
  unsigned tot = 0u;
  if (b < NB)
    for (int k = 0; k < CHUNKS; ++k) tot += hist[b * CHUNKS + k];
  int lane = b & 63, wid = b >> 6;
  unsigned x = tot;
#pragma unroll
  for (int off = 1; off < 64; off <<= 1) {
    unsigned y = __shfl_up(x, off);
    if (lane >= off) x += y;
  }
  __shared__ unsigned wtot[4];
  if (lane == 63) wtot[wid] = x;
  __syncthreads();
  unsigned wo = 0;
  for (int wq = 0; wq < wid; ++wq) wo += wtot[wq];
  unsigned excl = x + wo - tot;
  if (b <= NB) bb[b] = excl;
  if (b == 0) start[N_NODES] = N_EDGES;
}

// ---------------- Kernel H2: per-bucket exclusive scan across chunks -------
__global__ __launch_bounds__(256) void k_hist_scan(
    unsigned* __restrict__ hist, const unsigned* __restrict__ bb) {
  int b = blockIdx.x;
  int k = threadIdx.x;
  int lane = k & 63, wid = k >> 6;
  unsigned v = (k < CHUNKS) ? hist[b * CHUNKS + k] : 0u;
  unsigned x = v;
#pragma unroll
  for (int off = 1; off < 64; off <<= 1) {
    unsigned y = __shfl_up(x, off);
    if (lane >= off) x += y;
  }
  __shared__ unsigned wtot[4];
  if (lane == 63) wtot[wid] = x;
  __syncthreads();
  unsigned wo = 0;
  for (int wq = 0; wq < wid; ++wq) wo += wtot[wq];
  if (k < CHUNKS) hist[b * CHUNKS + k] = (x + wo) - v + bb[b];
}

// ---------------- Kernel S: scatter into bucket order, block-private -------
// int4 edge loads: 4 independent a1/a2 gathers in flight per thread.
__global__ __launch_bounds__(256) void k_scatter2(
    const int* __restrict__ rows, const int* __restrict__ cols,
    const float* __restrict__ a1, const float* __restrict__ a2,
    const unsigned* __restrict__ hist, int2* __restrict__ tmp2) {
  __shared__ unsigned lcur[NB];
  for (int b = threadIdx.x; b < NB; b += 256)
    lcur[b] = hist[b * CHUNKS + blockIdx.x];
  __syncthreads();
  int base = blockIdx.x * CE;
  for (int i = threadIdx.x * 4; i < CE; i += 1024) {
    int e = base + i;
    int4 r4 = *reinterpret_cast<const int4*>(&rows[e]);
    int4 c4 = *reinterpret_cast<const int4*>(&cols[e]);
    float s0 = a1[r4.x] + a2[c4.x];
    float s1 = a1[r4.y] + a2[c4.y];
    float s2 = a1[r4.z] + a2[c4.z];
    float s3 = a1[r4.w] + a2[c4.w];
    s0 = (s0 > 0.f) ? s0 : NEG_SLOPE * s0;
    s1 = (s1 > 0.f) ? s1 : NEG_SLOPE * s1;
    s2 = (s2 > 0.f) ? s2 : NEG_SLOPE * s2;
    s3 = (s3 > 0.f) ? s3 : NEG_SLOPE * s3;
    unsigned p0 = atomicAdd(&lcur[r4.x >> 8], 1u);
    tmp2[p0] = make_int2(((r4.x & 255) << 16) | c4.x, __float_as_int(s0));
    unsigned p1 = atomicAdd(&lcur[r4.y >> 8], 1u);
    tmp2[p1] = make_int2(((r4.y & 255) << 16) | c4.y, __float_as_int(s1));
    unsigned p2 = atomicAdd(&lcur[r4.z >> 8], 1u);
    tmp2[p2] = make_int2(((r4.z & 255) << 16) | c4.z, __float_as_int(s2));
    unsigned p3 = atomicAdd(&lcur[r4.w >> 8], 1u);
    tmp2[p3] = make_int2(((r4.w & 255) << 16) | c4.w, __float_as_int(s3));
  }
}

// ---------------- Kernel B: bucket -> CSR + fused softmax, packed es -------
__global__ __launch_bounds__(256) void k_bucket_final(
    const unsigned* __restrict__ bb, const int2* __restrict__ tmp2,
    unsigned* __restrict__ es, unsigned* __restrict__ start,
    float* __restrict__ dinv) {
  __shared__ unsigned lcnt[256];
  __shared__ unsigned lcur[256];
  __shared__ unsigned lmax[256];
  __shared__ float dsum[256];
  __shared__ unsigned wtot[4];
  int b = blockIdx.x;
  int rbase = b << 8;
  int nrows = N_NODES - rbase;
  if (nrows > 256) nrows = 256;
  lcnt[threadIdx.x] = 0u;
  lmax[threadIdx.x] = 0u;  // encodes "very negative"
  dsum[threadIdx.x] = 0.f;
  __syncthreads();
  unsigned base = bb[b];
  int n = (int)(bb[b + 1] - base);
  for (int i = threadIdx.x; i < n; i += 256) {
    int2 t = tmp2[base + i];
    int rlo = (t.x >> 16) & 255;
    atomicAdd(&lcnt[rlo], 1u);
    atomicMax(&lmax[rlo], enc_f32(__int_as_float(t.y)));
  }
  __syncthreads();
  // 256-wide exclusive scan of lcnt
  unsigned v = lcnt[threadIdx.x];
  int lane = threadIdx.x & 63, wid = threadIdx.x >> 6;
  unsigned x = v;
#pragma unroll
  for (int off = 1; off < 64; off <<= 1) {
    unsigned y = __shfl_up(x, off);
    if (lane >= off) x += y;
  }
  if (lane == 63) wtot[wid] = x;
  __syncthreads();
  unsigned wo = 0;
  for (int wq = 0; wq < wid; ++wq) wo += wtot[wq];
  unsigned excl = x + wo - v;
  lcur[threadIdx.x] = excl;
  if ((int)threadIdx.x < nrows) start[rbase + threadIdx.x] = base + excl;
  __syncthreads();
  // pass 2: scatter packed (col | bf16(ex)<<16), accumulate quantized d
  for (int i = threadIdx.x; i < n; i += 256) {
    int2 t = tmp2[base + i];
    int rlo = (t.x >> 16) & 255;
    float m = dec_f32(lmax[rlo]);
    float ex = __expf(__int_as_float(t.y) - m);
    unsigned exq = (unsigned)rne_bf16(ex);
    int dest = (int)atomicAdd(&lcur[rlo], 1u);
    es[base + dest] = ((unsigned)t.x & 0xFFFFu) | (exq << 16);
    atomicAdd(&dsum[rlo], __uint_as_float(exq << 16));
  }
  __syncthreads();
  if ((int)threadIdx.x < nrows)
    dinv[rbase + threadIdx.x] =
        (lcnt[threadIdx.x] > 0u) ? 1.0f / dsum[threadIdx.x] : 0.f;
}

// ---------------- Kernel 4: pure-fma aggregate, packed es, 16-deep ILP -----
__global__ __launch_bounds__(256) void k_row_agg(
    const unsigned* __restrict__ start, const float* __restrict__ dinv,
    const unsigned* __restrict__ es, const ushort* __restrict__ hb,
    float* __restrict__ out) {
  int gt = blockIdx.x * blockDim.x + threadIdx.x;
  int r = gt >> 6;
  int lane = gt & 63;
  if (r >= N_NODES) return;
  int beg = (int)start[r], end = (int)start[r + 1];

  float acc0 = 0.f, acc1 = 0.f, acc2 = 0.f, acc3 = 0.f;
  int i = beg;
  for (; i + 16 <= end; i += 16) {
    uint4 ea = *reinterpret_cast<const uint4*>(&es[i]);
    uint4 eb = *reinterpret_cast<const uint4*>(&es[i + 4]);
    uint4 ec = *reinterpret_cast<const uint4*>(&es[i + 8]);
    uint4 ed = *reinterpret_cast<const uint4*>(&es[i + 12]);
    float h0 = hload(hb, ea.x & 0xFFFFu, lane);
    float h1 = hload(hb, ea.y & 0xFFFFu, lane);
    float h2 = hload(hb, ea.z & 0xFFFFu, lane);
    float h3 = hload(hb, ea.w & 0xFFFFu, lane);
    float h4 = hload(hb, eb.x & 0xFFFFu, lane);
    float h5 = hload(hb, eb.y & 0xFFFFu, lane);
    float h6 = hload(hb, eb.z & 0xFFFFu, lane);
    float h7 = hload(hb, eb.w & 0xFFFFu, lane);
    float h8 = hload(hb, ec.x & 0xFFFFu, lane);
    float h9 = hload(hb, ec.y & 0xFFFFu, lane);
    float hA = hload(hb, ec.z & 0xFFFFu, lane);
    float hB = hload(hb, ec.w & 0xFFFFu, lane);
    float hC = hload(hb, ed.x & 0xFFFFu, lane);
    float hD = hload(hb, ed.y & 0xFFFFu, lane);
    float hE = hload(hb, ed.z & 0xFFFFu, lane);
    float hF = hload(hb, ed.w & 0xFFFFu, lane);
    acc0 = fmaf(__uint_as_float(ea.x & 0xFFFF0000u), h0, acc0);
    acc1 = fmaf(__uint_as_float(ea.y & 0xFFFF0000u), h1, acc1);
    acc2 = fmaf(__uint_as_float(ea.z & 0xFFFF0000u), h2, acc2);
    acc3 = fmaf(__uint_as_float(ea.w & 0xFFFF0000u), h3, acc3);
    acc0 = fmaf(__uint_as_float(eb.x & 0xFFFF0000u), h4, acc0);
    acc1 = fmaf(__uint_as_float(eb.y & 0xFFFF0000u), h5, acc1);
    acc2 = fmaf(__uint_as_float(eb.z & 0xFFFF0000u), h6, acc2);
    acc3 = fmaf(__uint_as_float(eb.w & 0xFFFF0000u), h7, acc3);
    acc0 = fmaf(__uint_as_float(ec.x & 0xFFFF0000u), h8, acc0);
    acc1 = fmaf(__uint_as_float(ec.y & 0xFFFF0000u), h9, acc1);
    acc2 = fmaf(__uint_as_float(ec.z & 0xFFFF0000u), hA, acc2);
    acc3 = fmaf(__uint_as_float(ec.w & 0xFFFF0000u), hB, acc3);
    acc0 = fmaf(__uint_as_float(ed.x & 0xFFFF0000u), hC, acc0);
    acc1 = fmaf(__uint_as_float(ed.y & 0xFFFF0000u), hD, acc1);
    acc2 = fmaf(__uint_as_float(ed.z & 0xFFFF0000u), hE, acc2);
    acc3 = fmaf(__uint_as_float(ed.w & 0xFFFF0000u), hF, acc3);
  }
  for (; i + 8 <= end; i += 8) {
    uint4 ea = *reinterpret_cast<const uint4*>(&es[i]);
    uint4 eb = *reinterpret_cast<const uint4*>(&es[i + 4]);
    float h0 = hload(hb, ea.x & 0xFFFFu, lane);
    float h1 = hload(hb, ea.y & 0xFFFFu, lane);
    float h2 = hload(hb, ea.z & 0xFFFFu, lane);
    float h3 = hload(hb, ea.w & 0xFFFFu, lane);
    float h4 = hload(hb, eb.x & 0xFFFFu, lane);
    float h5 = hload(hb, eb.y & 0xFFFFu, lane);
    float h6 = hload(hb, eb.z & 0xFFFFu, lane);
    float h7 = hload(hb, eb.w & 0xFFFFu, lane);
    acc0 = fmaf(__uint_as_float(ea.x & 0xFFFF0000u), h0, acc0);
    acc1 = fmaf(__uint_as_float(ea.y & 0xFFFF0000u), h1, acc1);
    acc2 = fmaf(__uint_as_float(ea.z & 0xFFFF0000u), h2, acc2);
    acc3 = fmaf(__uint_as_float(ea.w & 0xFFFF0000u), h3, acc3);
    acc0 = fmaf(__uint_as_float(eb.x & 0xFFFF0000u), h4, acc0);
    acc1 = fmaf(__uint_as_float(eb.y & 0xFFFF0000u), h5, acc1);
    acc2 = fmaf(__uint_as_float(eb.z & 0xFFFF0000u), h6, acc2);
    acc3 = fmaf(__uint_as_float(eb.w & 0xFFFF0000u), h7, acc3);
  }
  for (; i + 4 <= end; i += 4) {
    uint4 ea = *reinterpret_cast<const uint4*>(&es[i]);
    float h0 = hload(hb, ea.x & 0xFFFFu, lane);
    float h1 = hload(hb, ea.y & 0xFFFFu, lane);
    float h2 = hload(hb, ea.z & 0xFFFFu, lane);
    float h3 = hload(hb, ea.w & 0xFFFFu, lane);
    acc0 = fmaf(__uint_as_float(ea.x & 0xFFFF0000u), h0, acc0);
    acc1 = fmaf(__uint_as_float(ea.y & 0xFFFF0000u), h1, acc1);
    acc2 = fmaf(__uint_as_float(ea.z & 0xFFFF0000u), h2, acc2);
    acc3 = fmaf(__uint_as_float(ea.w & 0xFFFF0000u), h3, acc3);
  }
  for (; i < end; ++i) {
    unsigned e = es[i];
    float hv = hload(hb, e & 0xFFFFu, lane);
    acc0 = fmaf(__uint_as_float(e & 0xFFFF0000u), hv, acc0);
  }
  out[(size_t)r * D_OUT + lane] = ((acc0 + acc1) + (acc2 + acc3)) * dinv[r];
}

extern "C" void kernel_launch(void* const* d_in, const int* in_sizes, int n_in,
                              void* d_out, int out_size, void* d_ws, size_t ws_size,
                              hipStream_t stream) {
  const float* feat = (const float*)d_in[0];
  const int* eidx   = (const int*)d_in[1];   // [2, E] int32 (JAX x64 disabled)
  const float* W    = (const float*)d_in[3];
  const float* bias = (const float*)d_in[4];
  const float* a1w  = (const float*)d_in[5];
  const float* a1b  = (const float*)d_in[6];
  const float* a2w  = (const float*)d_in[7];
  const float* a2b  = (const float*)d_in[8];
  float* out = (float*)d_out;

  const int* rows = eidx;
  const int* cols = eidx + N_EDGES;

  // workspace layout (~17.1 MB); no memsets — everything rebuilt per call
  char* ws = (char*)d_ws;
  ushort*   hb    = (ushort*)ws;                     // 6.4 MB (bf16 h)
  unsigned* es    = (unsigned*)(ws + 6400000);       // 3.2 MB (packed)
  int2*     tmp2  = (int2*)(ws + 9600000);           // 6.4 MB
  float*    a1    = (float*)(ws + 16000000);         // 200 KB
  float*    a2    = (float*)(ws + 16200000);         // 200 KB
  unsigned* start = (unsigned*)(ws + 16400000);      // 200 KB (+4)
  float*    dinv  = (float*)(ws + 16600064);         // 200 KB
  unsigned* hist  = (unsigned*)(ws + 16800064);      // 196 KB (196*250 u32)
  unsigned* bb    = (unsigned*)(ws + 16996064);      // 788 B
  short8*   Bh    = (short8*)(ws + 16996864);        // 32 KB
  short8*   Bl    = (short8*)(ws + 17029632);        // 32 KB

  k_prep<<<8 + CHUNKS, 256, 0, stream>>>(W, Bh, Bl, rows, hist);
  {
    int waves = N_NODES / 16;  // 3125
    int blocks = (waves + 3) / 4;
    k_gemm_mfma<<<blocks, 256, 0, stream>>>(feat, Bh, Bl, bias, a1w, a1b, a2w,
                                            a2b, hb, a1, a2);
  }
  k_bucket_base<<<1, 256, 0, stream>>>(hist, bb, start);
  k_hist_scan<<<NB, 256, 0, stream>>>(hist, bb);
  k_scatter2<<<CHUNKS, 256, 0, stream>>>(rows, cols, a1, a2, hist, tmp2);
  k_bucket_final<<<NB, 256, 0, stream>>>(bb, tmp2, es, start, dinv);
  {
    long long threads = (long long)N_NODES * 64;
    int blocks = (int)((threads + 255) / 256);
    k_row_agg<<<blocks, 256, 0, stream>>>(start, dinv, es, hb, out);
  }
}

// Round 22
// 89.540 us; speedup vs baseline: 1.0594x; 1.0594x over previous
//
#include <hip/hip_runtime.h>

#define N_NODES 50000
#define N_EDGES 800000
#define D_IN 256
#define D_OUT 64
#define NEG_SLOPE 0.01f

#define NB 196      // coarse buckets: bucket = row >> 8
#define CHUNKS 200  // scatter blocks
#define CE 4000     // edges per scatter block (200*4000 = 800000 exactly)

typedef unsigned short ushort;
typedef short short8 __attribute__((ext_vector_type(8)));
typedef float f32x4 __attribute__((ext_vector_type(4)));

// Split f32 into hi/lo bf16 (truncation): a ≈ hi + lo, |err| ~ 2^-16 rel.
__device__ __forceinline__ void split2(float a, ushort& hi, ushort& lo) {
  unsigned ub = __float_as_uint(a);
  hi = (ushort)(ub >> 16);
  float hf = __uint_as_float(ub & 0xFFFF0000u);
  lo = (ushort)(__float_as_uint(a - hf) >> 16);
}

// f32 -> bf16 round-to-nearest-even
__device__ __forceinline__ ushort rne_bf16(float a) {
  unsigned u = __float_as_uint(a);
  return (ushort)((u + 0x7FFFu + ((u >> 16) & 1u)) >> 16);
}

// Monotone float<->uint encoding (atomicMax-able)
__device__ __forceinline__ unsigned enc_f32(float f) {
  unsigned u = __float_as_uint(f);
  return (u & 0x80000000u) ? ~u : (u | 0x80000000u);
}
__device__ __forceinline__ float dec_f32(unsigned u) {
  return (u & 0x80000000u) ? __uint_as_float(u ^ 0x80000000u)
                           : __uint_as_float(~u);
}

__device__ __forceinline__ float hload(const ushort* hb, unsigned col,
                                       int lane) {
  return __uint_as_float((unsigned)hb[(size_t)col * D_OUT + lane] << 16);
}

// ---------------- Kernel P: fused W-split (blocks 0..7) + histogram --------
__global__ __launch_bounds__(256) void k_prep(
    const float* __restrict__ W, short8* __restrict__ Bh,
    short8* __restrict__ Bl, const int* __restrict__ rows,
    unsigned* __restrict__ hist) {
  __shared__ unsigned lhist[NB];
  if (blockIdx.x < 8) {
    int t = blockIdx.x * 256 + threadIdx.x;  // 0..2047
    int lane = t & 63;
    int ct = (t >> 6) & 3;
    int ks = t >> 8;
    int k0 = ks * 32 + (lane >> 4) * 8;
    int col = ct * 16 + (lane & 15);
    short8 h8, l8;
#pragma unroll
    for (int j = 0; j < 8; ++j) {
      ushort hi, lo;
      split2(W[(size_t)(k0 + j) * D_OUT + col], hi, lo);
      h8[j] = (short)hi;
      l8[j] = (short)lo;
    }
    Bh[t] = h8;
    Bl[t] = l8;
  } else {
    int chunk = blockIdx.x - 8;
    for (int b = threadIdx.x; b < NB; b += 256) lhist[b] = 0u;
    __syncthreads();
    int base = chunk * CE;
    for (int i = threadIdx.x * 4; i < CE; i += 1024) {
      int4 r4 = *reinterpret_cast<const int4*>(&rows[base + i]);
      atomicAdd(&lhist[r4.x >> 8], 1u);
      atomicAdd(&lhist[r4.y >> 8], 1u);
      atomicAdd(&lhist[r4.z >> 8], 1u);
      atomicAdd(&lhist[r4.w >> 8], 1u);
    }
    __syncthreads();
    for (int b = threadIdx.x; b < NB; b += 256)
      hist[b * CHUNKS + chunk] = lhist[b];
  }
}

// ---------------- Kernel 1: h = X*W + b via bf16 MFMA (hi/lo split) --------
__global__ __launch_bounds__(256) void k_gemm_mfma(
    const float* __restrict__ feat, const short8* __restrict__ Bh,
    const short8* __restrict__ Bl, const float* __restrict__ bias,
    const float* __restrict__ a1w, const float* __restrict__ a1b,
    const float* __restrict__ a2w, const float* __restrict__ a2b,
    ushort* __restrict__ hb, float* __restrict__ a1, float* __restrict__ a2) {
  int wid = (blockIdx.x * 256 + threadIdx.x) >> 6;
  int lane = threadIdx.x & 63;
  if (wid >= N_NODES / 16) return;  // 3125 waves exactly
  int row0 = wid * 16;

  int arow = row0 + (lane & 15);
  const float* fp = feat + (size_t)arow * D_IN + ((lane >> 4) * 8);

  f32x4 acc[4];
#pragma unroll
  for (int ct = 0; ct < 4; ++ct) acc[ct] = (f32x4){0.f, 0.f, 0.f, 0.f};

#pragma unroll
  for (int ks = 0; ks < 8; ++ks) {
    float4 v0 = *reinterpret_cast<const float4*>(fp + ks * 32);
    float4 v1 = *reinterpret_cast<const float4*>(fp + ks * 32 + 4);
    float av[8] = {v0.x, v0.y, v0.z, v0.w, v1.x, v1.y, v1.z, v1.w};
    short8 ah, al;
#pragma unroll
    for (int j = 0; j < 8; ++j) {
      ushort hi, lo;
      split2(av[j], hi, lo);
      ah[j] = (short)hi;
      al[j] = (short)lo;
    }
#pragma unroll
    for (int ct = 0; ct < 4; ++ct) {
      short8 bh = Bh[(ks * 4 + ct) * 64 + lane];
      short8 bl = Bl[(ks * 4 + ct) * 64 + lane];
      acc[ct] = __builtin_amdgcn_mfma_f32_16x16x32_bf16(ah, bh, acc[ct], 0, 0, 0);
      acc[ct] = __builtin_amdgcn_mfma_f32_16x16x32_bf16(ah, bl, acc[ct], 0, 0, 0);
      acc[ct] = __builtin_amdgcn_mfma_f32_16x16x32_bf16(al, bh, acc[ct], 0, 0, 0);
    }
  }

  int lo16 = lane & 15;
  int hi4 = (lane >> 4) * 4;
  float bv[4], w1[4], w2[4];
#pragma unroll
  for (int ct = 0; ct < 4; ++ct) {
    bv[ct] = bias[ct * 16 + lo16];
    w1[ct] = a1w[ct * 16 + lo16];
    w2[ct] = a2w[ct * 16 + lo16];
  }
  float b1 = a1b[0], b2 = a2b[0];

#pragma unroll
  for (int r = 0; r < 4; ++r) {
    int row = row0 + hi4 + r;
    float s1 = 0.f, s2 = 0.f;
#pragma unroll
    for (int ct = 0; ct < 4; ++ct) {
      float hv = acc[ct][r] + bv[ct];
      hb[(size_t)row * D_OUT + ct * 16 + lo16] = rne_bf16(hv);
      s1 = fmaf(hv, w1[ct], s1);
      s2 = fmaf(hv, w2[ct], s2);
    }
#pragma unroll
    for (int off = 1; off < 16; off <<= 1) {
      s1 += __shfl_xor(s1, off);
      s2 += __shfl_xor(s2, off);
    }
    if (lo16 == 0) {
      a1[row] = s1 + b1;
      a2[row] = s2 + b2;
    }
  }
}

// ---------------- Kernel H1.5: bucket totals -> exclusive bases bb[] -------
__global__ __launch_bounds__(256) void k_bucket_base(
    const unsigned* __restrict__ hist, unsigned* __restrict__ bb,
    unsigned* __restrict__ start) {
  int b = threadIdx.x;
  unsigned tot = 0u;
  if (b < NB)
    for (int k = 0; k < CHUNKS; ++k) tot += hist[b * CHUNKS + k];
  int lane = b & 63, wid = b >> 6;
  unsigned x = tot;
#pragma unroll
  for (int off = 1; off < 64; off <<= 1) {
    unsigned y = __shfl_up(x, off);
    if (lane >= off) x += y;
  }
  __shared__ unsigned wtot[4];
  if (lane == 63) wtot[wid] = x;
  __syncthreads();
  unsigned wo = 0;
  for (int wq = 0; wq < wid; ++wq) wo += wtot[wq];
  unsigned excl = x + wo - tot;
  if (b <= NB) bb[b] = excl;
  if (b == 0) start[N_NODES] = N_EDGES;
}

// ---------------- Kernel H2: per-bucket exclusive scan across chunks -------
__global__ __launch_bounds__(256) void k_hist_scan(
    unsigned* __restrict__ hist, const unsigned* __restrict__ bb) {
  int b = blockIdx.x;
  int k = threadIdx.x;
  int lane = k & 63, wid = k >> 6;
  unsigned v = (k < CHUNKS) ? hist[b * CHUNKS + k] : 0u;
  unsigned x = v;
#pragma unroll
  for (int off = 1; off < 64; off <<= 1) {
    unsigned y = __shfl_up(x, off);
    if (lane >= off) x += y;
  }
  __shared__ unsigned wtot[4];
  if (lane == 63) wtot[wid] = x;
  __syncthreads();
  unsigned wo = 0;
  for (int wq = 0; wq < wid; ++wq) wo += wtot[wq];
  if (k < CHUNKS) hist[b * CHUNKS + k] = (x + wo) - v + bb[b];
}

// ---------------- Kernel S: scatter into bucket order, block-private -------
// int4 edge loads: 4 independent a1/a2 gathers in flight per thread.
__global__ __launch_bounds__(256) void k_scatter2(
    const int* __restrict__ rows, const int* __restrict__ cols,
    const float* __restrict__ a1, const float* __restrict__ a2,
    const unsigned* __restrict__ hist, int2* __restrict__ tmp2) {
  __shared__ unsigned lcur[NB];
  for (int b = threadIdx.x; b < NB; b += 256)
    lcur[b] = hist[b * CHUNKS + blockIdx.x];
  __syncthreads();
  int base = blockIdx.x * CE;
  for (int i = threadIdx.x * 4; i < CE; i += 1024) {
    int e = base + i;
    int4 r4 = *reinterpret_cast<const int4*>(&rows[e]);
    int4 c4 = *reinterpret_cast<const int4*>(&cols[e]);
    float s0 = a1[r4.x] + a2[c4.x];
    float s1 = a1[r4.y] + a2[c4.y];
    float s2 = a1[r4.z] + a2[c4.z];
    float s3 = a1[r4.w] + a2[c4.w];
    s0 = (s0 > 0.f) ? s0 : NEG_SLOPE * s0;
    s1 = (s1 > 0.f) ? s1 : NEG_SLOPE * s1;
    s2 = (s2 > 0.f) ? s2 : NEG_SLOPE * s2;
    s3 = (s3 > 0.f) ? s3 : NEG_SLOPE * s3;
    unsigned p0 = atomicAdd(&lcur[r4.x >> 8], 1u);
    tmp2[p0] = make_int2(((r4.x & 255) << 16) | c4.x, __float_as_int(s0));
    unsigned p1 = atomicAdd(&lcur[r4.y >> 8], 1u);
    tmp2[p1] = make_int2(((r4.y & 255) << 16) | c4.y, __float_as_int(s1));
    unsigned p2 = atomicAdd(&lcur[r4.z >> 8], 1u);
    tmp2[p2] = make_int2(((r4.z & 255) << 16) | c4.z, __float_as_int(s2));
    unsigned p3 = atomicAdd(&lcur[r4.w >> 8], 1u);
    tmp2[p3] = make_int2(((r4.w & 255) << 16) | c4.w, __float_as_int(s3));
  }
}

// ---------------- Kernel B: bucket -> CSR + fused softmax, packed es -------
__global__ __launch_bounds__(256) void k_bucket_final(
    const unsigned* __restrict__ bb, const int2* __restrict__ tmp2,
    unsigned* __restrict__ es, unsigned* __restrict__ start,
    float* __restrict__ dinv) {
  __shared__ unsigned lcnt[256];
  __shared__ unsigned lcur[256];
  __shared__ unsigned lmax[256];
  __shared__ float dsum[256];
  __shared__ unsigned wtot[4];
  int b = blockIdx.x;
  int rbase = b << 8;
  int nrows = N_NODES - rbase;
  if (nrows > 256) nrows = 256;
  lcnt[threadIdx.x] = 0u;
  lmax[threadIdx.x] = 0u;  // encodes "very negative"
  dsum[threadIdx.x] = 0.f;
  __syncthreads();
  unsigned base = bb[b];
  int n = (int)(bb[b + 1] - base);
  for (int i = threadIdx.x; i < n; i += 256) {
    int2 t = tmp2[base + i];
    int rlo = (t.x >> 16) & 255;
    atomicAdd(&lcnt[rlo], 1u);
    atomicMax(&lmax[rlo], enc_f32(__int_as_float(t.y)));
  }
  __syncthreads();
  // 256-wide exclusive scan of lcnt
  unsigned v = lcnt[threadIdx.x];
  int lane = threadIdx.x & 63, wid = threadIdx.x >> 6;
  unsigned x = v;
#pragma unroll
  for (int off = 1; off < 64; off <<= 1) {
    unsigned y = __shfl_up(x, off);
    if (lane >= off) x += y;
  }
  if (lane == 63) wtot[wid] = x;
  __syncthreads();
  unsigned wo = 0;
  for (int wq = 0; wq < wid; ++wq) wo += wtot[wq];
  unsigned excl = x + wo - v;
  lcur[threadIdx.x] = excl;
  if ((int)threadIdx.x < nrows) start[rbase + threadIdx.x] = base + excl;
  __syncthreads();
  // pass 2: scatter packed (col | bf16(ex)<<16), accumulate quantized d
  for (int i = threadIdx.x; i < n; i += 256) {
    int2 t = tmp2[base + i];
    int rlo = (t.x >> 16) & 255;
    float m = dec_f32(lmax[rlo]);
    float ex = __expf(__int_as_float(t.y) - m);
    unsigned exq = (unsigned)rne_bf16(ex);
    int dest = (int)atomicAdd(&lcur[rlo], 1u);
    es[base + dest] = ((unsigned)t.x & 0xFFFFu) | (exq << 16);
    atomicAdd(&dsum[rlo], __uint_as_float(exq << 16));
  }
  __syncthreads();
  if ((int)threadIdx.x < nrows)
    dinv[rbase + threadIdx.x] =
        (lcnt[threadIdx.x] > 0u) ? 1.0f / dsum[threadIdx.x] : 0.f;
}

// ---------------- Kernel 4: pure-fma aggregate, packed es, 16-deep ILP -----
__global__ __launch_bounds__(256) void k_row_agg(
    const unsigned* __restrict__ start, const float* __restrict__ dinv,
    const unsigned* __restrict__ es, const ushort* __restrict__ hb,
    float* __restrict__ out) {
  int gt = blockIdx.x * blockDim.x + threadIdx.x;
  int r = gt >> 6;
  int lane = gt & 63;
  if (r >= N_NODES) return;
  int beg = (int)start[r], end = (int)start[r + 1];

  float acc0 = 0.f, acc1 = 0.f, acc2 = 0.f, acc3 = 0.f;
  int i = beg;
  for (; i + 16 <= end; i += 16) {
    uint4 ea = *reinterpret_cast<const uint4*>(&es[i]);
    uint4 eb = *reinterpret_cast<const uint4*>(&es[i + 4]);
    uint4 ec = *reinterpret_cast<const uint4*>(&es[i + 8]);
    uint4 ed = *reinterpret_cast<const uint4*>(&es[i + 12]);
    float h0 = hload(hb, ea.x & 0xFFFFu, lane);
    float h1 = hload(hb, ea.y & 0xFFFFu, lane);
    float h2 = hload(hb, ea.z & 0xFFFFu, lane);
    float h3 = hload(hb, ea.w & 0xFFFFu, lane);
    float h4 = hload(hb, eb.x & 0xFFFFu, lane);
    float h5 = hload(hb, eb.y & 0xFFFFu, lane);
    float h6 = hload(hb, eb.z & 0xFFFFu, lane);
    float h7 = hload(hb, eb.w & 0xFFFFu, lane);
    float h8 = hload(hb, ec.x & 0xFFFFu, lane);
    float h9 = hload(hb, ec.y & 0xFFFFu, lane);
    float hA = hload(hb, ec.z & 0xFFFFu, lane);
    float hB = hload(hb, ec.w & 0xFFFFu, lane);
    float hC = hload(hb, ed.x & 0xFFFFu, lane);
    float hD = hload(hb, ed.y & 0xFFFFu, lane);
    float hE = hload(hb, ed.z & 0xFFFFu, lane);
    float hF = hload(hb, ed.w & 0xFFFFu, lane);
    acc0 = fmaf(__uint_as_float(ea.x & 0xFFFF0000u), h0, acc0);
    acc1 = fmaf(__uint_as_float(ea.y & 0xFFFF0000u), h1, acc1);
    acc2 = fmaf(__uint_as_float(ea.z & 0xFFFF0000u), h2, acc2);
    acc3 = fmaf(__uint_as_float(ea.w & 0xFFFF0000u), h3, acc3);
    acc0 = fmaf(__uint_as_float(eb.x & 0xFFFF0000u), h4, acc0);
    acc1 = fmaf(__uint_as_float(eb.y & 0xFFFF0000u), h5, acc1);
    acc2 = fmaf(__uint_as_float(eb.z & 0xFFFF0000u), h6, acc2);
    acc3 = fmaf(__uint_as_float(eb.w & 0xFFFF0000u), h7, acc3);
    acc0 = fmaf(__uint_as_float(ec.x & 0xFFFF0000u), h8, acc0);
    acc1 = fmaf(__uint_as_float(ec.y & 0xFFFF0000u), h9, acc1);
    acc2 = fmaf(__uint_as_float(ec.z & 0xFFFF0000u), hA, acc2);
    acc3 = fmaf(__uint_as_float(ec.w & 0xFFFF0000u), hB, acc3);
    acc0 = fmaf(__uint_as_float(ed.x & 0xFFFF0000u), hC, acc0);
    acc1 = fmaf(__uint_as_float(ed.y & 0xFFFF0000u), hD, acc1);
    acc2 = fmaf(__uint_as_float(ed.z & 0xFFFF0000u), hE, acc2);
    acc3 = fmaf(__uint_as_float(ed.w & 0xFFFF0000u), hF, acc3);
  }
  for (; i + 8 <= end; i += 8) {
    uint4 ea = *reinterpret_cast<const uint4*>(&es[i]);
    uint4 eb = *reinterpret_cast<const uint4*>(&es[i + 4]);
    float h0 = hload(hb, ea.x & 0xFFFFu, lane);
    float h1 = hload(hb, ea.y & 0xFFFFu, lane);
    float h2 = hload(hb, ea.z & 0xFFFFu, lane);
    float h3 = hload(hb, ea.w & 0xFFFFu, lane);
    float h4 = hload(hb, eb.x & 0xFFFFu, lane);
    float h5 = hload(hb, eb.y & 0xFFFFu, lane);
    float h6 = hload(hb, eb.z & 0xFFFFu, lane);
    float h7 = hload(hb, eb.w & 0xFFFFu, lane);
    acc0 = fmaf(__uint_as_float(ea.x & 0xFFFF0000u), h0, acc0);
    acc1 = fmaf(__uint_as_float(ea.y & 0xFFFF0000u), h1, acc1);
    acc2 = fmaf(__uint_as_float(ea.z & 0xFFFF0000u), h2, acc2);
    acc3 = fmaf(__uint_as_float(ea.w & 0xFFFF0000u), h3, acc3);
    acc0 = fmaf(__uint_as_float(eb.x & 0xFFFF0000u), h4, acc0);
    acc1 = fmaf(__uint_as_float(eb.y & 0xFFFF0000u), h5, acc1);
    acc2 = fmaf(__uint_as_float(eb.z & 0xFFFF0000u), h6, acc2);
    acc3 = fmaf(__uint_as_float(eb.w & 0xFFFF0000u), h7, acc3);
  }
  for (; i + 4 <= end; i += 4) {
    uint4 ea = *reinterpret_cast<const uint4*>(&es[i]);
    float h0 = hload(hb, ea.x & 0xFFFFu, lane);
    float h1 = hload(hb, ea.y & 0xFFFFu, lane);
    float h2 = hload(hb, ea.z & 0xFFFFu, lane);
    float h3 = hload(hb, ea.w & 0xFFFFu, lane);
    acc0 = fmaf(__uint_as_float(ea.x & 0xFFFF0000u), h0, acc0);
    acc1 = fmaf(__uint_as_float(ea.y & 0xFFFF0000u), h1, acc1);
    acc2 = fmaf(__uint_as_float(ea.z & 0xFFFF0000u), h2, acc2);
    acc3 = fmaf(__uint_as_float(ea.w & 0xFFFF0000u), h3, acc3);
  }
  for (; i < end; ++i) {
    unsigned e = es[i];
    float hv = hload(hb, e & 0xFFFFu, lane);
    acc0 = fmaf(__uint_as_float(e & 0xFFFF0000u), hv, acc0);
  }
  out[(size_t)r * D_OUT + lane] = ((acc0 + acc1) + (acc2 + acc3)) * dinv[r];
}

extern "C" void kernel_launch(void* const* d_in, const int* in_sizes, int n_in,
                              void* d_out, int out_size, void* d_ws, size_t ws_size,
                              hipStream_t stream) {
  const float* feat = (const float*)d_in[0];
  const int* eidx   = (const int*)d_in[1];   // [2, E] int32 (JAX x64 disabled)
  const float* W    = (const float*)d_in[3];
  const float* bias = (const float*)d_in[4];
  const float* a1w  = (const float*)d_in[5];
  const float* a1b  = (const float*)d_in[6];
  const float* a2w  = (const float*)d_in[7];
  const float* a2b  = (const float*)d_in[8];
  float* out = (float*)d_out;

  const int* rows = eidx;
  const int* cols = eidx + N_EDGES;

  // workspace layout (~17 MB); no memsets — everything rebuilt per call
  char* ws = (char*)d_ws;
  ushort*   hb    = (ushort*)ws;                     // 6.4 MB (bf16 h)
  unsigned* es    = (unsigned*)(ws + 6400000);       // 3.2 MB (packed)
  int2*     tmp2  = (int2*)(ws + 9600000);           // 6.4 MB
  float*    a1    = (float*)(ws + 16000000);         // 200 KB
  float*    a2    = (float*)(ws + 16200000);         // 200 KB
  unsigned* start = (unsigned*)(ws + 16400000);      // 200 KB (+4)
  float*    dinv  = (float*)(ws + 16600064);         // 200 KB
  unsigned* hist  = (unsigned*)(ws + 16800064);      // 157 KB
  unsigned* bb    = (unsigned*)(ws + 16956864);      // 788 B
  short8*   Bh    = (short8*)(ws + 16957696);        // 32 KB
  short8*   Bl    = (short8*)(ws + 16990464);        // 32 KB

  k_prep<<<8 + CHUNKS, 256, 0, stream>>>(W, Bh, Bl, rows, hist);
  {
    int waves = N_NODES / 16;  // 3125
    int blocks = (waves + 3) / 4;
    k_gemm_mfma<<<blocks, 256, 0, stream>>>(feat, Bh, Bl, bias, a1w, a1b, a2w,
                                            a2b, hb, a1, a2);
  }
  k_bucket_base<<<1, 256, 0, stream>>>(hist, bb, start);
  k_hist_scan<<<NB, 256, 0, stream>>>(hist, bb);
  k_scatter2<<<CHUNKS, 256, 0, stream>>>(rows, cols, a1, a2, hist, tmp2);
  k_bucket_final<<<NB, 256, 0, stream>>>(bb, tmp2, es, start, dinv);
  {
    long long threads = (long long)N_NODES * 64;
    int blocks = (int)((threads + 255) / 256);
    k_row_agg<<<blocks, 256, 0, stream>>>(start, dinv, es, hb, out);
  }
}